// Round 7
// baseline (284.895 us; speedup 1.0000x reference)
//
#include <hip/hip_runtime.h>
#include <cstdint>
#include <cmath>

#define BB   2
#define NN   2048
#define DIMM 1024
#define NHH  16
#define DHH  64
#define MMR  (BB * NN)

typedef _Float16 half8  __attribute__((ext_vector_type(8)));
typedef _Float16 half4v __attribute__((ext_vector_type(4)));
typedef float    f32x4  __attribute__((ext_vector_type(4)));

#define GLD16(gp, lp)                                                          \
  __builtin_amdgcn_global_load_lds(                                            \
      (const __attribute__((address_space(1))) unsigned int*)(gp),             \
      (__attribute__((address_space(3))) unsigned int*)(lp), 16, 0, 0)

// ---------------- convert x (fp32 -> f16) ----------------
__global__ __launch_bounds__(256) void cvt_x_kernel(const float* __restrict__ x,
                                                    _Float16* __restrict__ xh) {
  int i = (blockIdx.x * 256 + threadIdx.x) * 4;
  float4 v = *(const float4*)(x + i);
  half4v h;
  h[0] = (_Float16)v.x; h[1] = (_Float16)v.y;
  h[2] = (_Float16)v.z; h[3] = (_Float16)v.w;
  *(half4v*)(xh + i) = h;
}

// ---------------- transpose + convert weights: W[k][n] -> Wt[n][k] f16 ----------------
__global__ __launch_bounds__(256) void transpose_w_kernel(
    const float* __restrict__ Wq, const float* __restrict__ Wk,
    const float* __restrict__ Wv, const float* __restrict__ Wo,
    _Float16* __restrict__ wt) {
  __shared__ float tile[64][65];
  int z = blockIdx.z;
  const float* W = (z == 0) ? Wq : (z == 1) ? Wk : (z == 2) ? Wv : Wo;
  _Float16* dst = wt + (size_t)z * 1024 * 1024;
  int r0 = blockIdx.x * 64;
  int c0 = blockIdx.y * 64;
  int t = threadIdx.x;
  int tr = t >> 4;
  int tc = (t & 15) * 4;
#pragma unroll
  for (int i = 0; i < 4; ++i) {
    float4 v = *(const float4*)(W + (size_t)(r0 + tr + i * 16) * 1024 + c0 + tc);
    tile[tr + i * 16][tc + 0] = v.x;
    tile[tr + i * 16][tc + 1] = v.y;
    tile[tr + i * 16][tc + 2] = v.z;
    tile[tr + i * 16][tc + 3] = v.w;
  }
  __syncthreads();
#pragma unroll
  for (int i = 0; i < 4; ++i) {
    int nl = tr + i * 16;
    half4v hv;
    hv[0] = (_Float16)tile[tc + 0][nl];
    hv[1] = (_Float16)tile[tc + 1][nl];
    hv[2] = (_Float16)tile[tc + 2][nl];
    hv[3] = (_Float16)tile[tc + 3][nl];
    *(half4v*)(dst + (size_t)(c0 + nl) * 1024 + r0 + tc) = hv;
  }
}

// ---------------- QKV GEMM, m97 structure (128x128, BK=32, DMA staging) ----
// 4 waves 2x2; wave = 64x64 = 4x4 frags. LDS layout: [row][32] halfs, chunk
// position cl holds global chunk cl ^ ((row>>2)&3)  -> frag ds_read_b128 is
// 2-way (free). Epilogue: two 64-row Cs slabs (LDS union w/ staging), RoPE +
// scatter identical math to validated v1 epilogue.
__global__ __launch_bounds__(256, 3) void gemm_qkv_kernel(
    const _Float16* __restrict__ xh, const _Float16* __restrict__ wt,
    float* __restrict__ ko, float* __restrict__ vo,
    _Float16* __restrict__ qh, _Float16* __restrict__ kh,
    _Float16* __restrict__ vth) {
  __shared__ __align__(16) char smem[64 * 130 * 4];  // 33280 B >= 16384 staging
  _Float16* Ast = (_Float16*)smem;                   // [128][32]
  _Float16* Bst = (_Float16*)smem + 128 * 32;        // [128][32]
  float (*Cs)[130] = (float (*)[130])smem;
  const int m0 = blockIdx.x * 128;
  const int ngl = blockIdx.y * 128;
  const int mat = ngl >> 10;
  const int n0 = ngl & 1023;
  const int t = threadIdx.x;
  const int wv = t >> 6, lane = t & 63, l16 = lane & 15, quad = lane >> 4;
  const int wm = wv >> 1, wn = wv & 1;
  const _Float16* Ab = xh + (size_t)m0 * 1024;
  const _Float16* Bb = wt + (size_t)mat * 1024 * 1024 + (size_t)n0 * 1024;
  const _Float16* pa[2];
  const _Float16* pb[2];
#pragma unroll
  for (int j = 0; j < 2; ++j) {
    int cid = wv * 128 + j * 64 + lane;
    int r = cid >> 2, cl = cid & 3;
    int c = cl ^ ((r >> 2) & 3);
    pa[j] = Ab + (size_t)r * 1024 + c * 8;
    pb[j] = Bb + (size_t)r * 1024 + c * 8;
  }
  f32x4 acc[16] = {};
  for (int k0 = 0; k0 < 1024; k0 += 32) {
    __syncthreads();
#pragma unroll
    for (int j = 0; j < 2; ++j) {
      GLD16(pa[j] + k0, Ast + (wv * 128 + j * 64) * 8);
      GLD16(pb[j] + k0, Bst + (wv * 128 + j * 64) * 8);
    }
    __syncthreads();
    half8 a[4], b[4];
#pragma unroll
    for (int i = 0; i < 4; ++i) {
      int row = wm * 64 + i * 16 + l16;
      a[i] = *(const half8*)(Ast + row * 32 + (quad ^ ((row >> 2) & 3)) * 8);
    }
#pragma unroll
    for (int j = 0; j < 4; ++j) {
      int row = wn * 64 + j * 16 + l16;
      b[j] = *(const half8*)(Bst + row * 32 + (quad ^ ((row >> 2) & 3)) * 8);
    }
#pragma unroll
    for (int i = 0; i < 4; ++i)
#pragma unroll
      for (int j = 0; j < 4; ++j)
        acc[i * 4 + j] =
            __builtin_amdgcn_mfma_f32_16x16x32_f16(a[i], b[j], acc[i * 4 + j], 0, 0, 0);
  }
  // ---- epilogue: two 64-row slabs through Cs ----
  const int lr = t >> 2;
  const int cseg = (t & 3) * 32;
  const int hb = cseg & 64;
  const int dh0 = cseg & 63;
  const int h = (n0 + cseg) >> 6;
#pragma unroll 1
  for (int s = 0; s < 2; ++s) {
    __syncthreads();
    if (wm == s) {
#pragma unroll
      for (int i = 0; i < 4; ++i)
#pragma unroll
        for (int nt = 0; nt < 4; ++nt)
#pragma unroll
          for (int r = 0; r < 4; ++r)
            Cs[i * 16 + quad * 4 + r][wn * 64 + nt * 16 + l16] = acc[i * 4 + nt][r];
    }
    __syncthreads();
    const int m = m0 + s * 64 + lr;
    const int b = m >> 11, pos = m & 2047;
    const int bhh = b * NHH + h;
    float vals[32];
    if (mat == 2) {
#pragma unroll
      for (int j = 0; j < 32; ++j) vals[j] = Cs[lr][cseg + j];
    } else {
      float fpos = (float)pos;
#pragma unroll
      for (int j = 0; j < 32; ++j) {
        int dh = dh0 + j;
        int jd = dh & 31;
        float invf = exp2f((float)jd * -0.41524101186092029f);
        float ang = fpos * invf;
        float sv, cv;
        sincosf(ang, &sv, &cv);
        int pcol = hb + ((dh < 32) ? (2 * dh + 1) : (2 * (dh - 32)));
        float partner = (dh < 32) ? -Cs[lr][pcol] : Cs[lr][pcol];
        vals[j] = Cs[lr][cseg + j] * cv + partner * sv;
      }
    }
    size_t rowb = ((size_t)bhh * NN + pos) * DHH + dh0;
    if (mat == 0) {
#pragma unroll
      for (int j8 = 0; j8 < 4; ++j8) {
        half8 hv;
#pragma unroll
        for (int c2 = 0; c2 < 8; ++c2) hv[c2] = (_Float16)(vals[j8 * 8 + c2] * 0.125f);
        *(half8*)(qh + rowb + j8 * 8) = hv;
      }
    } else if (mat == 1) {
#pragma unroll
      for (int j4 = 0; j4 < 8; ++j4) {
        float4 o;
        o.x = vals[j4 * 4 + 0]; o.y = vals[j4 * 4 + 1];
        o.z = vals[j4 * 4 + 2]; o.w = vals[j4 * 4 + 3];
        *(float4*)(ko + rowb + j4 * 4) = o;
      }
#pragma unroll
      for (int j8 = 0; j8 < 4; ++j8) {
        half8 hv;
#pragma unroll
        for (int c2 = 0; c2 < 8; ++c2) hv[c2] = (_Float16)vals[j8 * 8 + c2];
        *(half8*)(kh + rowb + j8 * 8) = hv;
      }
    } else {
#pragma unroll
      for (int j4 = 0; j4 < 8; ++j4) {
        float4 o;
        o.x = vals[j4 * 4 + 0]; o.y = vals[j4 * 4 + 1];
        o.z = vals[j4 * 4 + 2]; o.w = vals[j4 * 4 + 3];
        *(float4*)(vo + rowb + j4 * 4) = o;
      }
#pragma unroll
      for (int j = 0; j < 32; ++j)
        vth[((size_t)bhh * DHH + dh0 + j) * NN + pos] = (_Float16)vals[j];
    }
  }
}

// ---------------- MFMA flash attention v3 (causal), f16 ----------------
__global__ __launch_bounds__(256, 2) void fattn_kernel(
    const _Float16* __restrict__ qh, const _Float16* __restrict__ kh,
    const _Float16* __restrict__ vth, _Float16* __restrict__ ah) {
  __shared__ __align__(16) _Float16 Kt[2][4096];
  __shared__ __align__(16) _Float16 Vt[2][4096];
  __shared__ __align__(16) _Float16 Pb[4][16][72];
  const int qb = 15 - (int)blockIdx.x;
  const int bh = blockIdx.y;
  const int t = threadIdx.x;
  const int wv = t >> 6, lane = t & 63, l16 = lane & 15, quad = lane >> 4;
  const int q0 = qb * 128;
  const _Float16* kg = kh + (size_t)bh * NN * DHH;
  const _Float16* vg = vth + (size_t)bh * DHH * NN;
  half8 qf[2][2];
#pragma unroll
  for (int qt2 = 0; qt2 < 2; ++qt2) {
    const _Float16* qp =
        qh + ((size_t)bh * NN + q0 + wv * 32 + qt2 * 16 + l16) * DHH + quad * 8;
    qf[qt2][0] = *(const half8*)qp;
    qf[qt2][1] = *(const half8*)(qp + 32);
  }
  half8 ones;
#pragma unroll
  for (int j = 0; j < 8; ++j) ones[j] = (_Float16)1.f;
  f32x4 o[2][4] = {};
  f32x4 ls[2] = {};
  const int ktmax = 2 * qb + 1;
#pragma unroll
  for (int iss = 0; iss < 2; ++iss) {
    int cid = iss * 256 + wv * 64 + lane;
    int row = cid >> 3;
    int c = (cid & 7) ^ (row & 7);
    GLD16(kg + (size_t)row * DHH + c * 8, &Kt[0][(iss * 256 + wv * 64) * 8]);
    GLD16(vg + (size_t)row * NN + c * 8, &Vt[0][(iss * 256 + wv * 64) * 8]);
  }
  int cur = 0;
  for (int kt = 0; kt <= ktmax; ++kt) {
    __syncthreads();
    if (kt < ktmax) {
      const _Float16* kn = kg + (size_t)(kt + 1) * 64 * DHH;
      const _Float16* vn = vg + (kt + 1) * 64;
      int nb = cur ^ 1;
#pragma unroll
      for (int iss = 0; iss < 2; ++iss) {
        int cid = iss * 256 + wv * 64 + lane;
        int row = cid >> 3;
        int c = (cid & 7) ^ (row & 7);
        GLD16(kn + (size_t)row * DHH + c * 8, &Kt[nb][(iss * 256 + wv * 64) * 8]);
        GLD16(vn + (size_t)row * NN + c * 8, &Vt[nb][(iss * 256 + wv * 64) * 8]);
      }
    }
    if (kt * 64 <= q0 + wv * 32 + 31) {
      half8 kf[4][2], vf[4][2];
      const _Float16* Kb = Kt[cur];
      const _Float16* Vb = Vt[cur];
#pragma unroll
      for (int nt = 0; nt < 4; ++nt) {
        int row = nt * 16 + l16;
        int r7 = row & 7;
        kf[nt][0] = *(const half8*)(Kb + row * 64 + ((quad ^ r7) * 8));
        kf[nt][1] = *(const half8*)(Kb + row * 64 + (((quad + 4) ^ r7) * 8));
        vf[nt][0] = *(const half8*)(Vb + row * 64 + ((quad ^ r7) * 8));
        vf[nt][1] = *(const half8*)(Vb + row * 64 + (((quad + 4) ^ r7) * 8));
      }
#pragma unroll
      for (int qt2 = 0; qt2 < 2; ++qt2) {
        int base = q0 + wv * 32 + qt2 * 16;
        if (kt * 64 <= base + 15) {
          f32x4 s4[4];
#pragma unroll
          for (int nt = 0; nt < 4; ++nt) {
            f32x4 z = {};
            z = __builtin_amdgcn_mfma_f32_16x16x32_f16(qf[qt2][0], kf[nt][0], z, 0, 0, 0);
            s4[nt] = __builtin_amdgcn_mfma_f32_16x16x32_f16(qf[qt2][1], kf[nt][1], z, 0, 0, 0);
          }
          if (kt * 64 + 63 > base) {
#pragma unroll
            for (int nt = 0; nt < 4; ++nt) {
              int key = kt * 64 + nt * 16 + l16;
#pragma unroll
              for (int r = 0; r < 4; ++r) {
                float p = (key > base + quad * 4 + r) ? 0.f : __expf(s4[nt][r]);
                Pb[wv][quad * 4 + r][nt * 16 + l16] = (_Float16)p;
              }
            }
          } else {
#pragma unroll
            for (int nt = 0; nt < 4; ++nt)
#pragma unroll
              for (int r = 0; r < 4; ++r)
                Pb[wv][quad * 4 + r][nt * 16 + l16] = (_Float16)__expf(s4[nt][r]);
          }
          asm volatile("s_waitcnt lgkmcnt(0)" ::: "memory");
          half8 pf0 = *(const half8*)&Pb[wv][l16][quad * 8];
          half8 pf1 = *(const half8*)&Pb[wv][l16][32 + quad * 8];
#pragma unroll
          for (int nt = 0; nt < 4; ++nt) {
            o[qt2][nt] = __builtin_amdgcn_mfma_f32_16x16x32_f16(pf0, vf[nt][0], o[qt2][nt], 0, 0, 0);
            o[qt2][nt] = __builtin_amdgcn_mfma_f32_16x16x32_f16(pf1, vf[nt][1], o[qt2][nt], 0, 0, 0);
          }
          ls[qt2] = __builtin_amdgcn_mfma_f32_16x16x32_f16(pf0, ones, ls[qt2], 0, 0, 0);
          ls[qt2] = __builtin_amdgcn_mfma_f32_16x16x32_f16(pf1, ones, ls[qt2], 0, 0, 0);
        }
      }
    }
    cur ^= 1;
  }
  const int b = bh >> 4, h = bh & 15;
#pragma unroll
  for (int qt2 = 0; qt2 < 2; ++qt2)
#pragma unroll
    for (int r = 0; r < 4; ++r) {
      float inv = 1.f / ls[qt2][r];
      int pos = q0 + wv * 32 + qt2 * 16 + quad * 4 + r;
      size_t ob = ((size_t)(b * NN + pos)) * DIMM + h * DHH;
#pragma unroll
      for (int nt = 0; nt < 4; ++nt)
        ah[ob + nt * 16 + l16] = (_Float16)(o[qt2][nt][r] * inv);
    }
}

// ---------------- out GEMM, m97 structure + bias ----------------
__global__ __launch_bounds__(256, 3) void gemm_out_kernel(
    const _Float16* __restrict__ ah, const _Float16* __restrict__ wot,
    const float* __restrict__ bo, float* __restrict__ out) {
  __shared__ __align__(16) _Float16 Ast[128 * 32];
  __shared__ __align__(16) _Float16 Bst[128 * 32];
  const int m0 = blockIdx.x * 128;
  const int n0 = blockIdx.y * 128;
  const int t = threadIdx.x;
  const int wv = t >> 6, lane = t & 63, l16 = lane & 15, quad = lane >> 4;
  const int wm = wv >> 1, wn = wv & 1;
  const _Float16* Ab = ah + (size_t)m0 * 1024;
  const _Float16* Bb = wot + (size_t)n0 * 1024;
  const _Float16* pa[2];
  const _Float16* pb[2];
#pragma unroll
  for (int j = 0; j < 2; ++j) {
    int cid = wv * 128 + j * 64 + lane;
    int r = cid >> 2, cl = cid & 3;
    int c = cl ^ ((r >> 2) & 3);
    pa[j] = Ab + (size_t)r * 1024 + c * 8;
    pb[j] = Bb + (size_t)r * 1024 + c * 8;
  }
  f32x4 acc[16] = {};
  for (int k0 = 0; k0 < 1024; k0 += 32) {
    __syncthreads();
#pragma unroll
    for (int j = 0; j < 2; ++j) {
      GLD16(pa[j] + k0, Ast + (wv * 128 + j * 64) * 8);
      GLD16(pb[j] + k0, Bst + (wv * 128 + j * 64) * 8);
    }
    __syncthreads();
    half8 a[4], b[4];
#pragma unroll
    for (int i = 0; i < 4; ++i) {
      int row = wm * 64 + i * 16 + l16;
      a[i] = *(const half8*)(Ast + row * 32 + (quad ^ ((row >> 2) & 3)) * 8);
    }
#pragma unroll
    for (int j = 0; j < 4; ++j) {
      int row = wn * 64 + j * 16 + l16;
      b[j] = *(const half8*)(Bst + row * 32 + (quad ^ ((row >> 2) & 3)) * 8);
    }
#pragma unroll
    for (int i = 0; i < 4; ++i)
#pragma unroll
      for (int j = 0; j < 4; ++j)
        acc[i * 4 + j] =
            __builtin_amdgcn_mfma_f32_16x16x32_f16(a[i], b[j], acc[i * 4 + j], 0, 0, 0);
  }
#pragma unroll
  for (int nt = 0; nt < 4; ++nt) {
    int col = n0 + wn * 64 + nt * 16 + l16;
    float bias = bo[col];
#pragma unroll
    for (int i = 0; i < 4; ++i)
#pragma unroll
      for (int r = 0; r < 4; ++r)
        out[(size_t)(m0 + wm * 64 + i * 16 + quad * 4 + r) * 1024 + col] =
            acc[i * 4 + nt][r] + bias;
  }
}

extern "C" void kernel_launch(void* const* d_in, const int* in_sizes, int n_in,
                              void* d_out, int out_size, void* d_ws, size_t ws_size,
                              hipStream_t stream) {
  (void)in_sizes; (void)n_in; (void)out_size; (void)ws_size;
  const float* x  = (const float*)d_in[0];
  const float* Wq = (const float*)d_in[1];
  const float* Wk = (const float*)d_in[2];
  const float* Wv = (const float*)d_in[3];
  const float* Wo = (const float*)d_in[4];
  const float* bo = (const float*)d_in[5];

  float* out = (float*)d_out;
  float* ko  = out + (size_t)MMR * DIMM;
  float* vo  = ko + (size_t)BB * NHH * NN * DHH;

  char* w = (char*)d_ws;
  _Float16* xh  = (_Float16*)w;                   // 8 MB (dead after gemm_qkv)
  _Float16* ah  = (_Float16*)w;                   // 8 MB (reuses xh region)
  _Float16* wt  = (_Float16*)(w + (8u << 20));    // 8 MB
  _Float16* qh  = (_Float16*)(w + (16u << 20));   // 8 MB (b,h,n,dh) roped, *0.125
  _Float16* kh  = (_Float16*)(w + (24u << 20));   // 8 MB (b,h,n,dh) roped
  _Float16* vth = (_Float16*)(w + (32u << 20));   // 8 MB (b,h,dh,n)

  hipLaunchKernelGGL(cvt_x_kernel, dim3(4096), dim3(256), 0, stream, x, xh);
  hipLaunchKernelGGL(transpose_w_kernel, dim3(16, 16, 4), dim3(256), 0, stream,
                     Wq, Wk, Wv, Wo, wt);
  hipLaunchKernelGGL(gemm_qkv_kernel, dim3(32, 24), dim3(256), 0, stream,
                     xh, wt, ko, vo, qh, kh, vth);
  hipLaunchKernelGGL(fattn_kernel, dim3(16, 32), dim3(256), 0, stream,
                     qh, kh, vth, ah);
  hipLaunchKernelGGL(gemm_out_kernel, dim3(32, 8), dim3(256), 0, stream,
                     ah, wt + (size_t)3 * 1024 * 1024, bo, out);
}

// Round 8
// 235.009 us; speedup vs baseline: 1.2123x; 1.2123x over previous
//
#include <hip/hip_runtime.h>
#include <cstdint>
#include <cmath>

#define BB   2
#define NN   2048
#define DIMM 1024
#define NHH  16
#define DHH  64
#define MMR  (BB * NN)

typedef _Float16 half8  __attribute__((ext_vector_type(8)));
typedef _Float16 half4v __attribute__((ext_vector_type(4)));
typedef float    f32x4  __attribute__((ext_vector_type(4)));

#define GLD16(gp, lp)                                                          \
  __builtin_amdgcn_global_load_lds(                                            \
      (const __attribute__((address_space(1))) unsigned int*)(gp),             \
      (__attribute__((address_space(3))) unsigned int*)(lp), 16, 0, 0)

// ---------------- convert x (fp32 -> f16) ----------------
__global__ __launch_bounds__(256) void cvt_x_kernel(const float* __restrict__ x,
                                                    _Float16* __restrict__ xh) {
  int i = (blockIdx.x * 256 + threadIdx.x) * 4;
  float4 v = *(const float4*)(x + i);
  half4v h;
  h[0] = (_Float16)v.x; h[1] = (_Float16)v.y;
  h[2] = (_Float16)v.z; h[3] = (_Float16)v.w;
  *(half4v*)(xh + i) = h;
}

// ---------------- transpose + convert weights: W[k][n] -> Wt[n][k] f16 ----------------
__global__ __launch_bounds__(256) void transpose_w_kernel(
    const float* __restrict__ Wq, const float* __restrict__ Wk,
    const float* __restrict__ Wv, const float* __restrict__ Wo,
    _Float16* __restrict__ wt) {
  __shared__ float tile[64][65];
  int z = blockIdx.z;
  const float* W = (z == 0) ? Wq : (z == 1) ? Wk : (z == 2) ? Wv : Wo;
  _Float16* dst = wt + (size_t)z * 1024 * 1024;
  int r0 = blockIdx.x * 64;
  int c0 = blockIdx.y * 64;
  int t = threadIdx.x;
  int tr = t >> 4;
  int tc = (t & 15) * 4;
#pragma unroll
  for (int i = 0; i < 4; ++i) {
    float4 v = *(const float4*)(W + (size_t)(r0 + tr + i * 16) * 1024 + c0 + tc);
    tile[tr + i * 16][tc + 0] = v.x;
    tile[tr + i * 16][tc + 1] = v.y;
    tile[tr + i * 16][tc + 2] = v.z;
    tile[tr + i * 16][tc + 3] = v.w;
  }
  __syncthreads();
#pragma unroll
  for (int i = 0; i < 4; ++i) {
    int nl = tr + i * 16;
    half4v hv;
    hv[0] = (_Float16)tile[tc + 0][nl];
    hv[1] = (_Float16)tile[tc + 1][nl];
    hv[2] = (_Float16)tile[tc + 2][nl];
    hv[3] = (_Float16)tile[tc + 3][nl];
    *(half4v*)(dst + (size_t)(c0 + nl) * 1024 + r0 + tc) = hv;
  }
}

// ---------------- QKV GEMM: R6 64x64 geometry + DMA staging ----------------
// K-loop: GLD16 DMA into [64][32] XOR-swizzled LDS (chunk cl holds global
// chunk cl^((r>>2)&3); frag ds_read_b128 2-way = free). Epilogue = R6's
// traffic-optimal RoPE/scatter (verified: 36MB fetch + 57MB write = ideal).
__global__ __launch_bounds__(256) void gemm_qkv_kernel(
    const _Float16* __restrict__ xh, const _Float16* __restrict__ wt,
    float* __restrict__ ko, float* __restrict__ vo,
    _Float16* __restrict__ qh, _Float16* __restrict__ kh,
    _Float16* __restrict__ vth) {
  __shared__ __align__(16) _Float16 Ast[64 * 32];
  __shared__ __align__(16) _Float16 Bst[64 * 32];
  __shared__ float Cs[64][65];
  const int m0  = blockIdx.x * 64;
  const int ngl = blockIdx.y * 64;
  const int mat = ngl >> 10;
  const int n0  = ngl & 1023;
  const _Float16* wb = wt + (size_t)mat * 1024 * 1024;
  const int t = threadIdx.x;
  const int wv = t >> 6, lane = t & 63, l16 = lane & 15, quad = lane >> 4;
  // staging source: cid = t covers 64 rows x 4 chunks of 16B
  const int r = t >> 2, cl = t & 3;
  const int c = cl ^ ((r >> 2) & 3);
  const _Float16* pa = xh + (size_t)(m0 + r) * 1024 + c * 8;
  const _Float16* pb = wb + (size_t)(n0 + r) * 1024 + c * 8;
  f32x4 acc[4] = {};
  const int arow = wv * 16 + l16;
  const int aoff = arow * 32 + (quad ^ ((arow >> 2) & 3)) * 8;
  for (int k0 = 0; k0 < 1024; k0 += 32) {
    __syncthreads();
    GLD16(pa + k0, Ast + wv * 512);
    GLD16(pb + k0, Bst + wv * 512);
    __syncthreads();
    half8 af = *(const half8*)(Ast + aoff);
#pragma unroll
    for (int nt = 0; nt < 4; ++nt) {
      int brow = nt * 16 + l16;
      half8 bf = *(const half8*)(Bst + brow * 32 + (quad ^ ((brow >> 2) & 3)) * 8);
      acc[nt] = __builtin_amdgcn_mfma_f32_16x16x32_f16(af, bf, acc[nt], 0, 0, 0);
    }
  }
#pragma unroll
  for (int nt = 0; nt < 4; ++nt)
#pragma unroll
    for (int rr = 0; rr < 4; ++rr)
      Cs[wv * 16 + quad * 4 + rr][nt * 16 + l16] = acc[nt][rr];
  __syncthreads();
  int lr = t >> 2;
  int cseg = (t & 3) * 16;
  int m = m0 + lr;
  int b = m >> 11;
  int pos = m & 2047;
  int h = n0 >> 6;
  int bhh = b * NHH + h;
  float vals[16];
  if (mat == 2) {
#pragma unroll
    for (int j = 0; j < 16; ++j) vals[j] = Cs[lr][cseg + j];
  } else {
    float fpos = (float)pos;
#pragma unroll
    for (int j = 0; j < 16; ++j) {
      int i = cseg + j;
      int jd = (i < 32) ? i : (i - 32);
      float invf = exp2f((float)jd * -0.41524101186092029f);
      float ang = fpos * invf;
      float sv, cv;
      sincosf(ang, &sv, &cv);
      float partner = (i < 32) ? -Cs[lr][2 * i + 1] : Cs[lr][2 * (i - 32)];
      vals[j] = Cs[lr][i] * cv + partner * sv;
    }
  }
  size_t rowb = ((size_t)bhh * NN + pos) * DHH + cseg;
  if (mat == 0) {
    half8 h0, h1;
#pragma unroll
    for (int j = 0; j < 8; ++j) { h0[j] = (_Float16)(vals[j] * 0.125f); h1[j] = (_Float16)(vals[8 + j] * 0.125f); }
    *(half8*)(qh + rowb) = h0;
    *(half8*)(qh + rowb + 8) = h1;
  } else if (mat == 1) {
#pragma unroll
    for (int j4 = 0; j4 < 4; ++j4) {
      float4 o;
      o.x = vals[j4 * 4 + 0]; o.y = vals[j4 * 4 + 1];
      o.z = vals[j4 * 4 + 2]; o.w = vals[j4 * 4 + 3];
      *(float4*)(ko + rowb + j4 * 4) = o;
    }
    half8 h0, h1;
#pragma unroll
    for (int j = 0; j < 8; ++j) { h0[j] = (_Float16)vals[j]; h1[j] = (_Float16)vals[8 + j]; }
    *(half8*)(kh + rowb) = h0;
    *(half8*)(kh + rowb + 8) = h1;
  } else {
#pragma unroll
    for (int j4 = 0; j4 < 4; ++j4) {
      float4 o;
      o.x = vals[j4 * 4 + 0]; o.y = vals[j4 * 4 + 1];
      o.z = vals[j4 * 4 + 2]; o.w = vals[j4 * 4 + 3];
      *(float4*)(vo + rowb + j4 * 4) = o;
    }
#pragma unroll
    for (int j = 0; j < 16; ++j)
      vth[((size_t)bhh * DHH + cseg + j) * NN + pos] = (_Float16)vals[j];
  }
}

// ---------------- MFMA flash attention v3 (causal), f16 ----------------
__global__ __launch_bounds__(256, 2) void fattn_kernel(
    const _Float16* __restrict__ qh, const _Float16* __restrict__ kh,
    const _Float16* __restrict__ vth, _Float16* __restrict__ ah) {
  __shared__ __align__(16) _Float16 Kt[2][4096];
  __shared__ __align__(16) _Float16 Vt[2][4096];
  __shared__ __align__(16) _Float16 Pb[4][16][72];
  const int qb = 15 - (int)blockIdx.x;
  const int bh = blockIdx.y;
  const int t = threadIdx.x;
  const int wv = t >> 6, lane = t & 63, l16 = lane & 15, quad = lane >> 4;
  const int q0 = qb * 128;
  const _Float16* kg = kh + (size_t)bh * NN * DHH;
  const _Float16* vg = vth + (size_t)bh * DHH * NN;
  half8 qf[2][2];
#pragma unroll
  for (int qt2 = 0; qt2 < 2; ++qt2) {
    const _Float16* qp =
        qh + ((size_t)bh * NN + q0 + wv * 32 + qt2 * 16 + l16) * DHH + quad * 8;
    qf[qt2][0] = *(const half8*)qp;
    qf[qt2][1] = *(const half8*)(qp + 32);
  }
  half8 ones;
#pragma unroll
  for (int j = 0; j < 8; ++j) ones[j] = (_Float16)1.f;
  f32x4 o[2][4] = {};
  f32x4 ls[2] = {};
  const int ktmax = 2 * qb + 1;
#pragma unroll
  for (int iss = 0; iss < 2; ++iss) {
    int cid = iss * 256 + wv * 64 + lane;
    int row = cid >> 3;
    int c = (cid & 7) ^ (row & 7);
    GLD16(kg + (size_t)row * DHH + c * 8, &Kt[0][(iss * 256 + wv * 64) * 8]);
    GLD16(vg + (size_t)row * NN + c * 8, &Vt[0][(iss * 256 + wv * 64) * 8]);
  }
  int cur = 0;
  for (int kt = 0; kt <= ktmax; ++kt) {
    __syncthreads();
    if (kt < ktmax) {
      const _Float16* kn = kg + (size_t)(kt + 1) * 64 * DHH;
      const _Float16* vn = vg + (kt + 1) * 64;
      int nb = cur ^ 1;
#pragma unroll
      for (int iss = 0; iss < 2; ++iss) {
        int cid = iss * 256 + wv * 64 + lane;
        int row = cid >> 3;
        int c = (cid & 7) ^ (row & 7);
        GLD16(kn + (size_t)row * DHH + c * 8, &Kt[nb][(iss * 256 + wv * 64) * 8]);
        GLD16(vn + (size_t)row * NN + c * 8, &Vt[nb][(iss * 256 + wv * 64) * 8]);
      }
    }
    if (kt * 64 <= q0 + wv * 32 + 31) {
      half8 kf[4][2], vf[4][2];
      const _Float16* Kb = Kt[cur];
      const _Float16* Vb = Vt[cur];
#pragma unroll
      for (int nt = 0; nt < 4; ++nt) {
        int row = nt * 16 + l16;
        int r7 = row & 7;
        kf[nt][0] = *(const half8*)(Kb + row * 64 + ((quad ^ r7) * 8));
        kf[nt][1] = *(const half8*)(Kb + row * 64 + (((quad + 4) ^ r7) * 8));
        vf[nt][0] = *(const half8*)(Vb + row * 64 + ((quad ^ r7) * 8));
        vf[nt][1] = *(const half8*)(Vb + row * 64 + (((quad + 4) ^ r7) * 8));
      }
#pragma unroll
      for (int qt2 = 0; qt2 < 2; ++qt2) {
        int base = q0 + wv * 32 + qt2 * 16;
        if (kt * 64 <= base + 15) {
          f32x4 s4[4];
#pragma unroll
          for (int nt = 0; nt < 4; ++nt) {
            f32x4 z = {};
            z = __builtin_amdgcn_mfma_f32_16x16x32_f16(qf[qt2][0], kf[nt][0], z, 0, 0, 0);
            s4[nt] = __builtin_amdgcn_mfma_f32_16x16x32_f16(qf[qt2][1], kf[nt][1], z, 0, 0, 0);
          }
          if (kt * 64 + 63 > base) {
#pragma unroll
            for (int nt = 0; nt < 4; ++nt) {
              int key = kt * 64 + nt * 16 + l16;
#pragma unroll
              for (int r = 0; r < 4; ++r) {
                float p = (key > base + quad * 4 + r) ? 0.f : __expf(s4[nt][r]);
                Pb[wv][quad * 4 + r][nt * 16 + l16] = (_Float16)p;
              }
            }
          } else {
#pragma unroll
            for (int nt = 0; nt < 4; ++nt)
#pragma unroll
              for (int r = 0; r < 4; ++r)
                Pb[wv][quad * 4 + r][nt * 16 + l16] = (_Float16)__expf(s4[nt][r]);
          }
          asm volatile("s_waitcnt lgkmcnt(0)" ::: "memory");
          half8 pf0 = *(const half8*)&Pb[wv][l16][quad * 8];
          half8 pf1 = *(const half8*)&Pb[wv][l16][32 + quad * 8];
#pragma unroll
          for (int nt = 0; nt < 4; ++nt) {
            o[qt2][nt] = __builtin_amdgcn_mfma_f32_16x16x32_f16(pf0, vf[nt][0], o[qt2][nt], 0, 0, 0);
            o[qt2][nt] = __builtin_amdgcn_mfma_f32_16x16x32_f16(pf1, vf[nt][1], o[qt2][nt], 0, 0, 0);
          }
          ls[qt2] = __builtin_amdgcn_mfma_f32_16x16x32_f16(pf0, ones, ls[qt2], 0, 0, 0);
          ls[qt2] = __builtin_amdgcn_mfma_f32_16x16x32_f16(pf1, ones, ls[qt2], 0, 0, 0);
        }
      }
    }
    cur ^= 1;
  }
  const int b = bh >> 4, h = bh & 15;
#pragma unroll
  for (int qt2 = 0; qt2 < 2; ++qt2)
#pragma unroll
    for (int r = 0; r < 4; ++r) {
      float inv = 1.f / ls[qt2][r];
      int pos = q0 + wv * 32 + qt2 * 16 + quad * 4 + r;
      size_t ob = ((size_t)(b * NN + pos)) * DIMM + h * DHH;
#pragma unroll
      for (int nt = 0; nt < 4; ++nt)
        ah[ob + nt * 16 + l16] = (_Float16)(o[qt2][nt][r] * inv);
    }
}

// ---------------- out GEMM: 64x64 geometry + DMA staging + bias ----------------
__global__ __launch_bounds__(256) void gemm_out_kernel(
    const _Float16* __restrict__ ah, const _Float16* __restrict__ wot,
    const float* __restrict__ bo, float* __restrict__ out) {
  __shared__ __align__(16) _Float16 Ast[64 * 32];
  __shared__ __align__(16) _Float16 Bst[64 * 32];
  const int m0 = blockIdx.x * 64;
  const int n0 = blockIdx.y * 64;
  const int t = threadIdx.x;
  const int wv = t >> 6, lane = t & 63, l16 = lane & 15, quad = lane >> 4;
  const int r = t >> 2, cl = t & 3;
  const int c = cl ^ ((r >> 2) & 3);
  const _Float16* pa = ah + (size_t)(m0 + r) * 1024 + c * 8;
  const _Float16* pb = wot + (size_t)(n0 + r) * 1024 + c * 8;
  f32x4 acc[4] = {};
  const int arow = wv * 16 + l16;
  const int aoff = arow * 32 + (quad ^ ((arow >> 2) & 3)) * 8;
  for (int k0 = 0; k0 < 1024; k0 += 32) {
    __syncthreads();
    GLD16(pa + k0, Ast + wv * 512);
    GLD16(pb + k0, Bst + wv * 512);
    __syncthreads();
    half8 af = *(const half8*)(Ast + aoff);
#pragma unroll
    for (int nt = 0; nt < 4; ++nt) {
      int brow = nt * 16 + l16;
      half8 bf = *(const half8*)(Bst + brow * 32 + (quad ^ ((brow >> 2) & 3)) * 8);
      acc[nt] = __builtin_amdgcn_mfma_f32_16x16x32_f16(af, bf, acc[nt], 0, 0, 0);
    }
  }
#pragma unroll
  for (int nt = 0; nt < 4; ++nt) {
    int col = n0 + nt * 16 + l16;
    float bias = bo[col];
#pragma unroll
    for (int rr = 0; rr < 4; ++rr) {
      out[(size_t)(m0 + wv * 16 + quad * 4 + rr) * 1024 + col] = acc[nt][rr] + bias;
    }
  }
}

extern "C" void kernel_launch(void* const* d_in, const int* in_sizes, int n_in,
                              void* d_out, int out_size, void* d_ws, size_t ws_size,
                              hipStream_t stream) {
  (void)in_sizes; (void)n_in; (void)out_size; (void)ws_size;
  const float* x  = (const float*)d_in[0];
  const float* Wq = (const float*)d_in[1];
  const float* Wk = (const float*)d_in[2];
  const float* Wv = (const float*)d_in[3];
  const float* Wo = (const float*)d_in[4];
  const float* bo = (const float*)d_in[5];

  float* out = (float*)d_out;
  float* ko  = out + (size_t)MMR * DIMM;
  float* vo  = ko + (size_t)BB * NHH * NN * DHH;

  char* w = (char*)d_ws;
  _Float16* xh  = (_Float16*)w;                   // 8 MB (dead after gemm_qkv)
  _Float16* ah  = (_Float16*)w;                   // 8 MB (reuses xh region)
  _Float16* wt  = (_Float16*)(w + (8u << 20));    // 8 MB
  _Float16* qh  = (_Float16*)(w + (16u << 20));   // 8 MB (b,h,n,dh) roped, *0.125
  _Float16* kh  = (_Float16*)(w + (24u << 20));   // 8 MB (b,h,n,dh) roped
  _Float16* vth = (_Float16*)(w + (32u << 20));   // 8 MB (b,h,dh,n)

  hipLaunchKernelGGL(cvt_x_kernel, dim3(4096), dim3(256), 0, stream, x, xh);
  hipLaunchKernelGGL(transpose_w_kernel, dim3(16, 16, 4), dim3(256), 0, stream,
                     Wq, Wk, Wv, Wo, wt);
  hipLaunchKernelGGL(gemm_qkv_kernel, dim3(64, 48), dim3(256), 0, stream,
                     xh, wt, ko, vo, qh, kh, vth);
  hipLaunchKernelGGL(fattn_kernel, dim3(16, 32), dim3(256), 0, stream,
                     qh, kh, vth, ah);
  hipLaunchKernelGGL(gemm_out_kernel, dim3(64, 16), dim3(256), 0, stream,
                     ah, wt + (size_t)3 * 1024 * 1024, bo, out);
}